// Round 3
// baseline (585.838 us; speedup 1.0000x reference)
//
#include <hip/hip_runtime.h>
#include <cstddef>

#define HH 720
#define WW 1280
#define FRAME 1843200            // 2*720*1280
#define FRAME4 460800            // FRAME/4
#define T_EVT 10
#define T_TOTAL 20
#define NBLK 256
#define NTHR 1024
#define NT (NBLK * NTHR)         // 262144 threads
#define ARRIVE (1u << 22)        // arrival token; spike count per step < 2^22

// Persistent device globals for the tiny scalar state.
__device__ unsigned g_minkey;
__device__ unsigned g_maxkey;
__device__ unsigned g_count[T_TOTAL];   // low 22 bits: spike count; bits 22+: arrivals
__device__ unsigned g_pbar[2];          // phase-transition barriers (A->B, B->C)

// Monotonic float<->uint key mapping (total order preserved).
__device__ __forceinline__ unsigned f2key(float f) {
    unsigned b = __float_as_uint(f);
    return b ^ ((unsigned)(((int)b) >> 31) | 0x80000000u);
}
__device__ __forceinline__ float key2f(unsigned k) {
    unsigned b = (k & 0x80000000u) ? (k ^ 0x80000000u) : ~k;
    return __uint_as_float(b);
}

__global__ void init_kernel() {
    if (threadIdx.x == 0) { g_minkey = 0xFFFFFFFFu; g_maxkey = 0u; }
    if (threadIdx.x < T_TOTAL) g_count[threadIdx.x] = 0u;
    if (threadIdx.x < 2) g_pbar[threadIdx.x] = 0u;
}

// Full-coherence grid barrier: __syncthreads drains every wave's vmcnt to L2;
// thread 0's __threadfence (agent) emits wbl2/inv so cross-XCD data written
// before the barrier is visible through plain loads after it.
__device__ __forceinline__ void phase_barrier(unsigned* ctr) {
    __syncthreads();
    if (threadIdx.x == 0) {
        __threadfence();  // release: waitcnt + L2 writeback
        __hip_atomic_fetch_add(ctr, 1u, __ATOMIC_RELAXED, __HIP_MEMORY_SCOPE_AGENT);
        unsigned v;
        do {
            __builtin_amdgcn_s_sleep(2);
            v = __hip_atomic_load(ctr, __ATOMIC_RELAXED, __HIP_MEMORY_SCOPE_AGENT);
        } while (v < NBLK);
        __threadfence();  // acquire: L1/L2 invalidate
    }
    __syncthreads();
}

__global__ __launch_bounds__(NTHR) void fused_kernel(const int* __restrict__ x,
                                                     const int* __restrict__ y,
                                                     const int* __restrict__ p,
                                                     const float* __restrict__ t,
                                                     float* __restrict__ out, int n) {
#pragma clang fp contract(off)
    const int gtid = blockIdx.x * NTHR + threadIdx.x;
    const int lane = threadIdx.x & 63, wv = threadIdx.x >> 6;
    float* hist = out + (size_t)T_EVT * FRAME;   // steps 10..19 region doubles as hist

    __shared__ unsigned sred[NTHR / 64];
    __shared__ unsigned sred2[NTHR / 64];
    __shared__ float sh_tmin, sh_tmax;
    __shared__ unsigned sh_total;

    // ---- Phase A: zero hist (10 frames) + t min/max ----
    {
        float4* hist4 = (float4*)hist;
        const float4 z = make_float4(0.f, 0.f, 0.f, 0.f);
        for (int i = gtid; i < T_EVT * FRAME4; i += NT) hist4[i] = z;

        unsigned mn = 0xFFFFFFFFu, mx = 0u;
        for (int i = gtid; i < n; i += NT) {
            unsigned k = f2key(t[i]);
            mn = mn < k ? mn : k;
            mx = mx > k ? mx : k;
        }
        for (int off = 32; off > 0; off >>= 1) {
            unsigned omn = (unsigned)__shfl_down((int)mn, off, 64);
            unsigned omx = (unsigned)__shfl_down((int)mx, off, 64);
            mn = mn < omn ? mn : omn;
            mx = mx > omx ? mx : omx;
        }
        if (lane == 0) { sred[wv] = mn; sred2[wv] = mx; }
        __syncthreads();
        if (threadIdx.x == 0) {
#pragma unroll
            for (int i = 1; i < NTHR / 64; ++i) {
                mn = mn < sred[i] ? mn : sred[i];
                mx = mx > sred2[i] ? mx : sred2[i];
            }
            atomicMin(&g_minkey, mn);
            atomicMax(&g_maxkey, mx);
        }
    }

    phase_barrier(&g_pbar[0]);
    if (threadIdx.x == 0) {
        sh_tmin = key2f(__hip_atomic_load(&g_minkey, __ATOMIC_RELAXED,
                                          __HIP_MEMORY_SCOPE_AGENT));
        sh_tmax = key2f(__hip_atomic_load(&g_maxkey, __ATOMIC_RELAXED,
                                          __HIP_MEMORY_SCOPE_AGENT));
    }
    __syncthreads();

    // ---- Phase B: scatter events into hist ----
    {
        const float tmin = sh_tmin, tmax = sh_tmax;
        const bool span = tmax > tmin;
        const float inv_span_mul = (float)(10.0 - 1e-6);
        for (int i = gtid; i < n; i += NT) {
            float tv = t[i];
            float tn;
            if (span) {
                // exact reference op order: ((t - tmin) / denom) * (10 - 1e-6)
                tn = (tv - tmin) / (tmax - tmin) * inv_span_mul;
            } else {
                tn = 0.0f;
            }
            int ti = (int)tn;
            ti = ti < 0 ? 0 : (ti > T_EVT - 1 ? T_EVT - 1 : ti);
            int xi = x[i]; xi = xi < 0 ? 0 : (xi > WW - 1 ? WW - 1 : xi);
            int yi = y[i]; yi = yi < 0 ? 0 : (yi > HH - 1 ? HH - 1 : yi);
            int ci = p[i];
            size_t off = (size_t)ti * FRAME + (size_t)ci * (HH * WW)
                       + (size_t)yi * WW + xi;
            atomicAdd(hist + off, 1.0f);
        }
    }

    phase_barrier(&g_pbar[1]);

    // ---- Phase C: 20-step LIF scan ----
    // Step s reads hist frame at out[(10+s)*FRAME]; step 10+s overwrites that
    // region with spikes at the SAME per-thread indices -> no cross-thread
    // visibility needed for frame data, only the packed count atomic.
    {
        const float decay = (float)0.9048374180359595;  // float32(exp(-1/10))
        float4 mem0 = make_float4(0.f, 0.f, 0.f, 0.f);
        float4 mem1 = make_float4(0.f, 0.f, 0.f, 0.f);
        const bool has1 = (gtid + NT) < FRAME4;
        float thr = 1.0f;

        for (int s = 0; s < T_TOTAL; ++s) {
            const float4* h4 = (const float4*)(out + (size_t)(T_EVT + s) * FRAME);
            float4* o4 = (float4*)(out + (size_t)s * FRAME);
            int cnt = 0;

            {
                float4 f = (s < T_EVT) ? h4[gtid] : make_float4(0.f, 0.f, 0.f, 0.f);
                float4 m, spk;
                m.x = mem0.x * decay; m.x = m.x + f.x;
                m.y = mem0.y * decay; m.y = m.y + f.y;
                m.z = mem0.z * decay; m.z = m.z + f.z;
                m.w = mem0.w * decay; m.w = m.w + f.w;
                spk.x = (m.x >= thr) ? 1.0f : 0.0f;
                spk.y = (m.y >= thr) ? 1.0f : 0.0f;
                spk.z = (m.z >= thr) ? 1.0f : 0.0f;
                spk.w = (m.w >= thr) ? 1.0f : 0.0f;
                o4[gtid] = spk;
                mem0.x = m.x - spk.x * thr;
                mem0.y = m.y - spk.y * thr;
                mem0.z = m.z - spk.z * thr;
                mem0.w = m.w - spk.w * thr;
                cnt += (int)spk.x + (int)spk.y + (int)spk.z + (int)spk.w;
            }
            if (has1) {
                int i1 = gtid + NT;
                float4 f = (s < T_EVT) ? h4[i1] : make_float4(0.f, 0.f, 0.f, 0.f);
                float4 m, spk;
                m.x = mem1.x * decay; m.x = m.x + f.x;
                m.y = mem1.y * decay; m.y = m.y + f.y;
                m.z = mem1.z * decay; m.z = m.z + f.z;
                m.w = mem1.w * decay; m.w = m.w + f.w;
                spk.x = (m.x >= thr) ? 1.0f : 0.0f;
                spk.y = (m.y >= thr) ? 1.0f : 0.0f;
                spk.z = (m.z >= thr) ? 1.0f : 0.0f;
                spk.w = (m.w >= thr) ? 1.0f : 0.0f;
                o4[i1] = spk;
                mem1.x = m.x - spk.x * thr;
                mem1.y = m.y - spk.y * thr;
                mem1.z = m.z - spk.z * thr;
                mem1.w = m.w - spk.w * thr;
                cnt += (int)spk.x + (int)spk.y + (int)spk.z + (int)spk.w;
            }

            for (int off = 32; off > 0; off >>= 1) cnt += __shfl_down(cnt, off, 64);
            if (lane == 0) sred[wv] = (unsigned)cnt;
            __syncthreads();
            if (threadIdx.x == 0) {
                unsigned b = 0;
#pragma unroll
                for (int i = 0; i < NTHR / 64; ++i) b += sred[i];
                __hip_atomic_fetch_add(&g_count[s], b + ARRIVE,
                                       __ATOMIC_RELAXED, __HIP_MEMORY_SCOPE_AGENT);
                unsigned v;
                do {
                    __builtin_amdgcn_s_sleep(1);
                    v = __hip_atomic_load(&g_count[s], __ATOMIC_RELAXED,
                                          __HIP_MEMORY_SCOPE_AGENT);
                } while ((v >> 22) != NBLK);
                sh_total = v & (ARRIVE - 1u);
            }
            __syncthreads();
            float rate = (float)sh_total / 1843200.0f;  // exact count; IEEE div = mean
            thr = thr + 0.1f * (rate - 0.1f);
            thr = fminf(fmaxf(thr, 0.1f), 10.0f);
        }
    }
}

extern "C" void kernel_launch(void* const* d_in, const int* in_sizes, int n_in,
                              void* d_out, int out_size, void* d_ws, size_t ws_size,
                              hipStream_t stream) {
    const int*   x = (const int*)d_in[0];
    const int*   y = (const int*)d_in[1];
    const int*   p = (const int*)d_in[2];
    const float* t = (const float*)d_in[3];
    float* out = (float*)d_out;
    int n = in_sizes[0];

    init_kernel<<<1, 64, 0, stream>>>();

    dim3 g(NBLK), b(NTHR);
    void* args[] = { (void*)&x, (void*)&y, (void*)&p, (void*)&t,
                     (void*)&out, (void*)&n };
    hipLaunchCooperativeKernel((void*)fused_kernel, g, b, args, 0, stream);
}

// Round 4
// 546.015 us; speedup vs baseline: 1.0729x; 1.0729x over previous
//
#include <hip/hip_runtime.h>
#include <cstddef>

#define HH 720
#define WW 1280
#define FRAME 1843200            // 2*720*1280
#define FRAME4 460800            // FRAME/4
#define T_EVT 10
#define T_TOTAL 20
#define NBLK 256
#define NTHR 1024
#define NT (NBLK * NTHR)         // 262144 scan threads
#define ARRIVE (1u << 22)        // arrival token; spike count per step < 2^22

// Persistent device globals for the tiny scalar state.
__device__ unsigned g_minkey;
__device__ unsigned g_maxkey;
__device__ unsigned g_count[T_TOTAL];   // low 22 bits: spike count; bits 22+: arrivals

// Monotonic float<->uint key mapping (total order preserved).
__device__ __forceinline__ unsigned f2key(float f) {
    unsigned b = __float_as_uint(f);
    return b ^ ((unsigned)(((int)b) >> 31) | 0x80000000u);
}
__device__ __forceinline__ float key2f(unsigned k) {
    unsigned b = (k & 0x80000000u) ? (k ^ 0x80000000u) : ~k;
    return __uint_as_float(b);
}

__global__ void init_kernel() {
    if (threadIdx.x == 0) { g_minkey = 0xFFFFFFFFu; g_maxkey = 0u; }
    if (threadIdx.x < T_TOTAL) g_count[threadIdx.x] = 0u;
}

// min/max of t (float4-vectorized), fused with zeroing the histogram region.
// Kernel boundary before scatter_kernel guarantees both complete + coherent.
__global__ void minmax_zero_kernel(const float* __restrict__ t, int n,
                                   float4* __restrict__ hist4) {
    const int gtid = blockIdx.x * blockDim.x + threadIdx.x;
    const int gstride = gridDim.x * blockDim.x;

    const float4 z = make_float4(0.f, 0.f, 0.f, 0.f);
    for (int i = gtid; i < T_EVT * FRAME4; i += gstride) hist4[i] = z;

    unsigned mn = 0xFFFFFFFFu, mx = 0u;
    const int n4 = n >> 2;
    const float4* t4 = (const float4*)t;
    for (int i = gtid; i < n4; i += gstride) {
        float4 tv = t4[i];
        unsigned k0 = f2key(tv.x), k1 = f2key(tv.y);
        unsigned k2 = f2key(tv.z), k3 = f2key(tv.w);
        unsigned a = k0 < k1 ? k0 : k1, b = k2 < k3 ? k2 : k3;
        unsigned c = a < b ? a : b;
        mn = mn < c ? mn : c;
        a = k0 > k1 ? k0 : k1; b = k2 > k3 ? k2 : k3;
        c = a > b ? a : b;
        mx = mx > c ? mx : c;
    }
    for (int i = (n4 << 2) + gtid; i < n; i += gstride) {  // tail
        unsigned k = f2key(t[i]);
        mn = mn < k ? mn : k;
        mx = mx > k ? mx : k;
    }
    for (int off = 32; off > 0; off >>= 1) {
        unsigned omn = (unsigned)__shfl_down((int)mn, off, 64);
        unsigned omx = (unsigned)__shfl_down((int)mx, off, 64);
        mn = mn < omn ? mn : omn;
        mx = mx > omx ? mx : omx;
    }
    __shared__ unsigned smn[16], smx[16];
    int lane = threadIdx.x & 63, wv = threadIdx.x >> 6;
    if (lane == 0) { smn[wv] = mn; smx[wv] = mx; }
    __syncthreads();
    if (threadIdx.x == 0) {
        int nw = blockDim.x >> 6;
        for (int i = 1; i < nw; ++i) {
            mn = mn < smn[i] ? mn : smn[i];
            mx = mx > smx[i] ? mx : smx[i];
        }
        atomicMin(&g_minkey, mn);
        atomicMax(&g_maxkey, mx);
    }
}

__device__ __forceinline__ void commit_event(int xi, int yi, int ci, float tv,
                                             float tmin, float tmax, bool span,
                                             float* __restrict__ hist) {
#pragma clang fp contract(off)
    float tn;
    if (span) {
        // exact reference op order: ((t - tmin) / denom) * (10 - 1e-6), fp32 IEEE
        tn = (tv - tmin) / (tmax - tmin) * (float)(10.0 - 1e-6);
    } else {
        tn = 0.0f;
    }
    int ti = (int)tn;                     // trunc toward zero, tn >= 0
    ti = ti < 0 ? 0 : (ti > T_EVT - 1 ? T_EVT - 1 : ti);
    xi = xi < 0 ? 0 : (xi > WW - 1 ? WW - 1 : xi);
    yi = yi < 0 ? 0 : (yi > HH - 1 ? HH - 1 : yi);
    size_t off = (size_t)ti * FRAME + (size_t)ci * (HH * WW) + (size_t)yi * WW + xi;
    atomicAdd(hist + off, 1.0f);
}

// 4 events per thread, int4/float4 loads, fire-and-forget atomics.
__global__ void scatter_kernel(const int* __restrict__ x, const int* __restrict__ y,
                               const int* __restrict__ p, const float* __restrict__ t,
                               float* __restrict__ hist, int n) {
    const int g = blockIdx.x * blockDim.x + threadIdx.x;
    const int i0 = g << 2;
    if (i0 >= n) return;
    const float tmin = key2f(g_minkey);
    const float tmax = key2f(g_maxkey);
    const bool span = tmax > tmin;
    if (i0 + 3 < n) {
        int4   xs = ((const int4*)x)[g];
        int4   ys = ((const int4*)y)[g];
        int4   ps = ((const int4*)p)[g];
        float4 ts = ((const float4*)t)[g];
        commit_event(xs.x, ys.x, ps.x, ts.x, tmin, tmax, span, hist);
        commit_event(xs.y, ys.y, ps.y, ts.y, tmin, tmax, span, hist);
        commit_event(xs.z, ys.z, ps.z, ts.z, tmin, tmax, span, hist);
        commit_event(xs.w, ys.w, ps.w, ts.w, tmin, tmax, span, hist);
    } else {
        for (int i = i0; i < n; ++i)
            commit_event(x[i], y[i], p[i], t[i], tmin, tmax, span, hist);
    }
}

// Cooperative scan. Next hist frame is prefetched BEFORE the barrier spin so
// memory latency overlaps barrier latency; only VALU+reduce+barrier remain on
// the critical path. Step 19's count is never consumed -> no final barrier.
// hist frames live in out[(10+s)*FRAME]; step 10+s overwrites that region at
// the SAME per-thread indices -> no cross-thread visibility needed for frame
// data, only the packed count atomic.
__global__ __launch_bounds__(NTHR) void scan_kernel(float* __restrict__ out) {
#pragma clang fp contract(off)
    const float decay = (float)0.9048374180359595;  // float32(exp(-1/10))
    const int gtid = blockIdx.x * NTHR + threadIdx.x;
    const int lane = threadIdx.x & 63, wv = threadIdx.x >> 6;
    const float4 z = make_float4(0.f, 0.f, 0.f, 0.f);

    float4 mem0 = z, mem1 = z;
    const bool has1 = (gtid + NT) < FRAME4;   // k=0 always valid (NT <= FRAME4)
    float thr = 1.0f;

    __shared__ unsigned sred[NTHR / 64];
    __shared__ unsigned sh_total;

    // preload step 0's frame
    float4 f0, f1;
    {
        const float4* h = (const float4*)(out + (size_t)T_EVT * FRAME);
        f0 = h[gtid];
        f1 = has1 ? h[gtid + NT] : z;
    }

    for (int s = 0; s < T_TOTAL; ++s) {
        float4* o4 = (float4*)(out + (size_t)s * FRAME);
        int cnt = 0;

        {   // k = 0
            float4 m, spk;
            m.x = mem0.x * decay; m.x = m.x + f0.x;
            m.y = mem0.y * decay; m.y = m.y + f0.y;
            m.z = mem0.z * decay; m.z = m.z + f0.z;
            m.w = mem0.w * decay; m.w = m.w + f0.w;
            spk.x = (m.x >= thr) ? 1.0f : 0.0f;
            spk.y = (m.y >= thr) ? 1.0f : 0.0f;
            spk.z = (m.z >= thr) ? 1.0f : 0.0f;
            spk.w = (m.w >= thr) ? 1.0f : 0.0f;
            o4[gtid] = spk;
            mem0.x = m.x - spk.x * thr;
            mem0.y = m.y - spk.y * thr;
            mem0.z = m.z - spk.z * thr;
            mem0.w = m.w - spk.w * thr;
            cnt += (int)spk.x + (int)spk.y + (int)spk.z + (int)spk.w;
        }
        if (has1) {   // k = 1
            float4 m, spk;
            m.x = mem1.x * decay; m.x = m.x + f1.x;
            m.y = mem1.y * decay; m.y = m.y + f1.y;
            m.z = mem1.z * decay; m.z = m.z + f1.z;
            m.w = mem1.w * decay; m.w = m.w + f1.w;
            spk.x = (m.x >= thr) ? 1.0f : 0.0f;
            spk.y = (m.y >= thr) ? 1.0f : 0.0f;
            spk.z = (m.z >= thr) ? 1.0f : 0.0f;
            spk.w = (m.w >= thr) ? 1.0f : 0.0f;
            o4[gtid + NT] = spk;
            mem1.x = m.x - spk.x * thr;
            mem1.y = m.y - spk.y * thr;
            mem1.z = m.z - spk.z * thr;
            mem1.w = m.w - spk.w * thr;
            cnt += (int)spk.x + (int)spk.y + (int)spk.z + (int)spk.w;
        }

        // prefetch step s+1's frame (doesn't depend on thr -> overlaps barrier)
        if (s + 1 < T_EVT) {
            const float4* hn = (const float4*)(out + (size_t)(T_EVT + s + 1) * FRAME);
            f0 = hn[gtid];
            f1 = has1 ? hn[gtid + NT] : z;
        } else {
            f0 = z; f1 = z;
        }

        if (s == T_TOTAL - 1) break;   // last step's count is never consumed

        for (int off = 32; off > 0; off >>= 1) cnt += __shfl_down(cnt, off, 64);
        if (lane == 0) sred[wv] = (unsigned)cnt;
        __syncthreads();
        if (threadIdx.x == 0) {
            unsigned b = 0;
#pragma unroll
            for (int i = 0; i < NTHR / 64; ++i) b += sred[i];
            __hip_atomic_fetch_add(&g_count[s], b + ARRIVE,
                                   __ATOMIC_RELAXED, __HIP_MEMORY_SCOPE_AGENT);
            unsigned v;
            do {
                __builtin_amdgcn_s_sleep(1);
                v = __hip_atomic_load(&g_count[s], __ATOMIC_RELAXED,
                                      __HIP_MEMORY_SCOPE_AGENT);
            } while ((v >> 22) != NBLK);
            sh_total = v & (ARRIVE - 1u);
        }
        __syncthreads();
        float rate = (float)sh_total / 1843200.0f;  // exact count; IEEE div = mean
        thr = thr + 0.1f * (rate - 0.1f);
        thr = fminf(fmaxf(thr, 0.1f), 10.0f);
    }
}

extern "C" void kernel_launch(void* const* d_in, const int* in_sizes, int n_in,
                              void* d_out, int out_size, void* d_ws, size_t ws_size,
                              hipStream_t stream) {
    const int*   x = (const int*)d_in[0];
    const int*   y = (const int*)d_in[1];
    const int*   p = (const int*)d_in[2];
    const float* t = (const float*)d_in[3];
    float* out = (float*)d_out;
    const int n = in_sizes[0];

    float* hist = out + (size_t)T_EVT * FRAME;   // steps 10..19 region doubles as hist

    init_kernel<<<1, 64, 0, stream>>>();
    minmax_zero_kernel<<<1024, 256, 0, stream>>>(t, n, (float4*)hist);
    scatter_kernel<<<(n / 4 + 255) / 256, 256, 0, stream>>>(x, y, p, t, hist, n);

    dim3 g(NBLK), b(NTHR);
    void* args[] = { (void*)&out };
    hipLaunchCooperativeKernel((void*)scan_kernel, g, b, args, 0, stream);
}